// Round 12
// baseline (332.928 us; speedup 1.0000x reference)
//
#include <hip/hip_runtime.h>
#include <hip/hip_bf16.h>
#include <hip/hip_cooperative_groups.h>

namespace cg = cooperative_groups;

#define N_NODES 50000
#define N_EDGES 800000
#define IN_DIM  256
#define OUT_DIM 64
#define NRANGE  8      // XCD dst-range partitions
#define RSPAN   6250   // 50000/8
#define CB      256    // coop grid blocks (1 per CU)
#define CT      1024   // coop block threads
#define SCHUNK  196    // ceil(50000/256) scan chunk per block

using bf16x8 = __attribute__((ext_vector_type(8))) __bf16;
using f32x4  = __attribute__((ext_vector_type(4))) float;
using u32x4  = __attribute__((ext_vector_type(4))) unsigned int;

// ---------------------------------------------------------------------------
// Cooperative preprocessing: zero cnt -> edge normalize + degree -> scan
// (block-local, block0 over partials, add-base) -> XCD-partitioned scatter.
// One kernel, grid.sync() between phases; per-thread scan state in registers.
// ---------------------------------------------------------------------------
__global__ __launch_bounds__(CT) void preprocess_coop(
    const void* __restrict__ edges,
    int* __restrict__ src32, int* __restrict__ dst32,
    int* __restrict__ cnt, int* __restrict__ off, int* __restrict__ cursor,
    float* __restrict__ dinv, int* __restrict__ partial,
    int* __restrict__ csr_src)
{
    cg::grid_group grid = cg::this_grid();
    const int b = blockIdx.x, t = threadIdx.x;
    const int gtid = b * CT + t;
    __shared__ int sm[256];
    __shared__ int nz;

    // P0: zero cnt (12500 int4)
    if (gtid < 12500) ((int4*)cnt)[gtid] = make_int4(0, 0, 0, 0);

    // dtype probe (block-local; int64 values < 50000 -> odd words all 0)
    if (t == 0) nz = 0;
    __syncthreads();
    if (t < 256 && ((const unsigned*)edges)[2 * t + 1] != 0u) nz = 1;
    __syncthreads();
    const int is64 = (nz == 0);

    grid.sync();

    // P1: normalize edges to int32 + degree count
    for (long long e = gtid; e < N_EDGES; e += (long long)CB * CT) {
        int s, d;
        if (is64) {
            s = (int)((const long long*)edges)[e];
            d = (int)((const long long*)edges)[N_EDGES + e];
        } else {
            s = ((const int*)edges)[e];
            d = ((const int*)edges)[N_EDGES + e];
        }
        src32[e] = s;
        dst32[e] = d;
        atomicAdd(&cnt[d], 1);
    }

    grid.sync();

    // P2a: block-local scan of chunk [b*SCHUNK, +SCHUNK)
    const int i = b * SCHUNK + t;
    int v = 0, incl = 0;
    if (t < 256) {
        v = (t < SCHUNK && i < N_NODES) ? cnt[i] : 0;
        if (t < SCHUNK && i < N_NODES) dinv[i] = rsqrtf((float)(v + 1));
        sm[t] = v;
    }
    __syncthreads();
    for (int s = 1; s < 256; s <<= 1) {
        int tv = 0;
        if (t < 256 && t >= s) tv = sm[t - s];
        __syncthreads();
        if (t < 256 && t >= s) sm[t] += tv;
        __syncthreads();
    }
    if (t < 256) incl = sm[t];
    if (t == 255) partial[b] = incl;

    grid.sync();

    // P2b: block 0 scans the 256 partials
    if (b == 0) {
        int pv = 0;
        if (t < 256) { pv = partial[t]; sm[t] = pv; }
        __syncthreads();
        for (int s = 1; s < 256; s <<= 1) {
            int tv = 0;
            if (t < 256 && t >= s) tv = sm[t - s];
            __syncthreads();
            if (t < 256 && t >= s) sm[t] += tv;
            __syncthreads();
        }
        if (t < 256) partial[t] = sm[t] - pv;   // exclusive base per chunk
        if (t == 255) partial[256] = sm[255];   // grand total
    }

    grid.sync();

    // P2c: off/cursor = local exclusive + chunk base
    if (t < 256 && t < SCHUNK && i < N_NODES) {
        int o = incl - v + partial[b];
        off[i] = o;
        cursor[i] = o;
    }
    if (b == 0 && t == 0) off[N_NODES] = partial[256];

    grid.sync();

    // P3: XCD-partitioned scatter (range r's CSR window merges in one L2)
    {
        const int range = b & (NRANGE - 1);
        const int sub   = b >> 3;               // 0..31
        const int rlo = range * RSPAN, rhi = rlo + RSPAN;
        for (long long e = (long long)sub * CT + t; e < N_EDGES; e += 32LL * CT) {
            int d = dst32[e];
            if (d >= rlo && d < rhi) {
                int pos = atomicAdd(&cursor[d], 1);
                csr_src[pos] = src32[e];
            }
        }
    }
}

// ---------------------------------------------------------------------------
// MFMA split-bf16 helpers (truncation split; 3 MFMA, rel err ~2^-16).
// ---------------------------------------------------------------------------
union BFu { u32x4 u; bf16x8 b; };

__device__ __forceinline__ void split_pack(float x0, float x1,
                                           unsigned& hi, unsigned& lo) {
    unsigned u0 = __float_as_uint(x0), u1 = __float_as_uint(x1);
    hi = (u1 & 0xFFFF0000u) | (u0 >> 16);
    float h0 = __uint_as_float(u0 & 0xFFFF0000u);
    float h1 = __uint_as_float(u1 & 0xFFFF0000u);
    unsigned r0 = __float_as_uint(x0 - h0);
    unsigned r1 = __float_as_uint(x1 - h1);
    lo = (r1 & 0xFFFF0000u) | (r0 >> 16);
}

template <int K>
__device__ __forceinline__ void gemm_body(int gbid, const float* __restrict__ X,
                                          const float* __restrict__ W,
                                          float* __restrict__ H) {
    constexpr int NS = K / 32;
    const int lane = threadIdx.x & 63;
    const int wave = threadIdx.x >> 6;
    const int lm   = lane & 15;
    const int kg   = lane >> 4;

    BFu bhi[NS], blo[NS];
#pragma unroll
    for (int s = 0; s < NS; ++s) {
#pragma unroll
        for (int jp = 0; jp < 4; ++jp) {
            float w0 = W[(size_t)(s * 32 + kg * 8 + 2 * jp)     * 64 + wave * 16 + lm];
            float w1 = W[(size_t)(s * 32 + kg * 8 + 2 * jp + 1) * 64 + wave * 16 + lm];
            unsigned h, l;
            split_pack(w0, w1, h, l);
            bhi[s].u[jp] = h;
            blo[s].u[jp] = l;
        }
    }

    const int r0 = gbid * 64;
    const float* xr[4];
#pragma unroll
    for (int m = 0; m < 4; ++m) {
        int r = r0 + m * 16 + lm;
        xr[m] = X + (size_t)((r < N_NODES) ? r : (N_NODES - 1)) * K;
    }

    f32x4 acc[4] = {};

#pragma unroll
    for (int s = 0; s < NS; ++s) {
#pragma unroll
        for (int m = 0; m < 4; ++m) {
            float4 a0 = *(const float4*)(xr[m] + s * 32 + kg * 8);
            float4 a1 = *(const float4*)(xr[m] + s * 32 + kg * 8 + 4);
            BFu ah, al;
            unsigned h, l;
            split_pack(a0.x, a0.y, h, l); ah.u[0] = h; al.u[0] = l;
            split_pack(a0.z, a0.w, h, l); ah.u[1] = h; al.u[1] = l;
            split_pack(a1.x, a1.y, h, l); ah.u[2] = h; al.u[2] = l;
            split_pack(a1.z, a1.w, h, l); ah.u[3] = h; al.u[3] = l;
            acc[m] = __builtin_amdgcn_mfma_f32_16x16x32_bf16(ah.b, bhi[s].b, acc[m], 0, 0, 0);
            acc[m] = __builtin_amdgcn_mfma_f32_16x16x32_bf16(ah.b, blo[s].b, acc[m], 0, 0, 0);
            acc[m] = __builtin_amdgcn_mfma_f32_16x16x32_bf16(al.b, bhi[s].b, acc[m], 0, 0, 0);
        }
    }

    const int c = wave * 16 + lm;
#pragma unroll
    for (int m = 0; m < 4; ++m) {
#pragma unroll
        for (int t = 0; t < 4; ++t) {
            int r = r0 + m * 16 + kg * 4 + t;
            if (r < N_NODES) H[(size_t)r * 64 + c] = acc[m][t];
        }
    }
}

template <int K>
__global__ __launch_bounds__(256) void gemm_mfma(const float* __restrict__ X,
                                                 const float* __restrict__ W,
                                                 float* __restrict__ H) {
    gemm_body<K>((int)blockIdx.x, X, W, H);
}

// ---------------------------------------------------------------------------
// Fused agg(layer1) + gemm(layer2): 1024 thr = 16 waves = 16 nodes/block.
// Wave wv aggregates node (blockIdx*16+wv): z1 = relu(agg*dd + b1) -> LDS
// z[16][68] (pad 68 -> 2-way-free banks). Waves 0..3 then compute
// H2[16 rows] = z1 @ W2 via split-bf16 MFMA (A from LDS, row=lm, k=cols).
// ---------------------------------------------------------------------------
__global__ __launch_bounds__(1024) void agg1_gemm2(const float* __restrict__ H,
                                                   const float* __restrict__ dinv,
                                                   const float* __restrict__ b1v,
                                                   const int* __restrict__ off,
                                                   const int* __restrict__ csr_src,
                                                   const float* __restrict__ W2,
                                                   float* __restrict__ H2) {
    __shared__ float z[16][68];
    const int wv   = threadIdx.x >> 6;    // node-in-block 0..15
    const int lane = threadIdx.x & 63;
    const int node = blockIdx.x * 16 + wv;

    // --- aggregate node (same math as agg_csr) ---
    float dd = dinv[node];
    float acc = H[(size_t)node * 64 + lane] * dd;
    int beg = off[node], end = off[node + 1];
    for (int k0 = beg; k0 < end; k0 += 64) {
        int myk = k0 + lane;
        int   s_l  = (myk < end) ? csr_src[myk] : 0;
        float ds_l = (myk < end) ? dinv[s_l] : 0.f;
        int cnt = min(64, end - k0);
        int i = 0;
        for (; i + 8 <= cnt; i += 8) {
            float v[8], nm[8];
#pragma unroll
            for (int jj = 0; jj < 8; ++jj) {
                int s  = __shfl(s_l, i + jj);
                nm[jj] = __shfl(ds_l, i + jj);
                v[jj]  = H[(size_t)s * 64 + lane];
            }
#pragma unroll
            for (int jj = 0; jj < 8; ++jj) acc = fmaf(v[jj], nm[jj], acc);
        }
        for (; i < cnt; ++i) {
            int   s  = __shfl(s_l, i);
            float nm = __shfl(ds_l, i);
            acc = fmaf(H[(size_t)s * 64 + lane], nm, acc);
        }
    }
    z[wv][lane] = fmaxf(fmaf(acc, dd, b1v[lane]), 0.f);
    __syncthreads();

    // --- gemm2 on the 16-row z1 tile (waves 0..3, 16-col slices) ---
    if (wv < 4) {
        const int lm = lane & 15;
        const int kg = lane >> 4;

        BFu bhi[2], blo[2];
#pragma unroll
        for (int s = 0; s < 2; ++s) {
#pragma unroll
            for (int jp = 0; jp < 4; ++jp) {
                float w0 = W2[(size_t)(s * 32 + kg * 8 + 2 * jp)     * 64 + wv * 16 + lm];
                float w1 = W2[(size_t)(s * 32 + kg * 8 + 2 * jp + 1) * 64 + wv * 16 + lm];
                unsigned h, l;
                split_pack(w0, w1, h, l);
                bhi[s].u[jp] = h;
                blo[s].u[jp] = l;
            }
        }

        f32x4 acc2 = {};
#pragma unroll
        for (int s = 0; s < 2; ++s) {
            BFu ah, al;
            unsigned h, l;
            float a0 = z[lm][s * 32 + kg * 8 + 0], a1 = z[lm][s * 32 + kg * 8 + 1];
            float a2 = z[lm][s * 32 + kg * 8 + 2], a3 = z[lm][s * 32 + kg * 8 + 3];
            float a4 = z[lm][s * 32 + kg * 8 + 4], a5 = z[lm][s * 32 + kg * 8 + 5];
            float a6 = z[lm][s * 32 + kg * 8 + 6], a7 = z[lm][s * 32 + kg * 8 + 7];
            split_pack(a0, a1, h, l); ah.u[0] = h; al.u[0] = l;
            split_pack(a2, a3, h, l); ah.u[1] = h; al.u[1] = l;
            split_pack(a4, a5, h, l); ah.u[2] = h; al.u[2] = l;
            split_pack(a6, a7, h, l); ah.u[3] = h; al.u[3] = l;
            acc2 = __builtin_amdgcn_mfma_f32_16x16x32_bf16(ah.b, bhi[s].b, acc2, 0, 0, 0);
            acc2 = __builtin_amdgcn_mfma_f32_16x16x32_bf16(ah.b, blo[s].b, acc2, 0, 0, 0);
            acc2 = __builtin_amdgcn_mfma_f32_16x16x32_bf16(al.b, bhi[s].b, acc2, 0, 0, 0);
        }

        const int c = wv * 16 + lm;
#pragma unroll
        for (int t = 0; t < 4; ++t) {
            int r = blockIdx.x * 16 + kg * 4 + t;
            H2[(size_t)r * 64 + c] = acc2[t];
        }
    }
}

// ---------------------------------------------------------------------------
// Final gather-aggregate (layer 2): one wave per dst node.
// out = relu( (Σ_s H2[s]*dinv[s] + H2[d]*dd) * dd + b2 )
// ---------------------------------------------------------------------------
__global__ __launch_bounds__(256) void agg_csr(const float* __restrict__ H,
                                               const float* __restrict__ dinv,
                                               const float* __restrict__ b,
                                               const int* __restrict__ off,
                                               const int* __restrict__ csr_src,
                                               float* __restrict__ out) {
    int wid  = (blockIdx.x * 256 + threadIdx.x) >> 6;
    int lane = threadIdx.x & 63;
    if (wid >= N_NODES) return;
    float dd = dinv[wid];
    float acc = H[(size_t)wid * 64 + lane] * dd;
    int beg = off[wid], end = off[wid + 1];
    for (int k0 = beg; k0 < end; k0 += 64) {
        int myk = k0 + lane;
        int   s_l  = (myk < end) ? csr_src[myk] : 0;
        float ds_l = (myk < end) ? dinv[s_l] : 0.f;
        int cnt = min(64, end - k0);
        int i = 0;
        for (; i + 8 <= cnt; i += 8) {
            float v[8], nm[8];
#pragma unroll
            for (int jj = 0; jj < 8; ++jj) {
                int s  = __shfl(s_l, i + jj);
                nm[jj] = __shfl(ds_l, i + jj);
                v[jj]  = H[(size_t)s * 64 + lane];
            }
#pragma unroll
            for (int jj = 0; jj < 8; ++jj) acc = fmaf(v[jj], nm[jj], acc);
        }
        for (; i < cnt; ++i) {
            int   s  = __shfl(s_l, i);
            float nm = __shfl(ds_l, i);
            acc = fmaf(H[(size_t)s * 64 + lane], nm, acc);
        }
    }
    out[(size_t)wid * 64 + lane] = fmaxf(fmaf(acc, dd, b[lane]), 0.f);
}

extern "C" void kernel_launch(void* const* d_in, const int* in_sizes, int n_in,
                              void* d_out, int out_size, void* d_ws, size_t ws_size,
                              hipStream_t stream) {
    const float* feat = (const float*)d_in[0];
    const float* W1   = (const float*)d_in[1];
    const float* b1   = (const float*)d_in[2];
    const float* W2   = (const float*)d_in[3];
    const float* b2   = (const float*)d_in[4];
    const void*  edges = d_in[5];
    float* out = (float*)d_out;

    char* ws = (char*)d_ws;
    const size_t SZ_N = 200704;   // >= 50001 ints
    const size_t SZ_E = (size_t)N_EDGES * 4;
    int*   partial = (int*)ws;                                   // 257 ints (2 KB)
    int*   cnt     = (int*)(ws + 2048);
    float* dinv    = (float*)(ws + 2048 + SZ_N);
    int*   off     = (int*)(ws + 2048 + 2 * SZ_N);               // 50001 ints
    int*   cursor  = (int*)(ws + 2048 + 3 * SZ_N);
    int*   src32   = (int*)(ws + 2048 + 4 * SZ_N);               // 3.2 MB
    int*   dst32   = (int*)(ws + 2048 + 4 * SZ_N + SZ_E);        // 3.2 MB
    int*   csr_src = (int*)(ws + 2048 + 4 * SZ_N + 2 * SZ_E);    // 3.2 MB
    float* H1      = (float*)(ws + 2048 + 4 * SZ_N + 3 * SZ_E);  // 12.8 MB
    float* H2      = H1 + (size_t)N_NODES * 64;                  // 12.8 MB

    const int NB_G = (N_NODES + 63) / 64;         // 782
    const int NB_W = (N_NODES * 64 + 255) / 256;  // 12500
    const int NB_F = N_NODES / 16;                // 3125

    // Preprocessing: one cooperative kernel (zero, norm+deg, scan, scatter).
    {
        void* args[] = {(void*)&edges, (void*)&src32, (void*)&dst32, (void*)&cnt,
                        (void*)&off, (void*)&cursor, (void*)&dinv, (void*)&partial,
                        (void*)&csr_src};
        hipLaunchCooperativeKernel((void*)preprocess_coop, dim3(CB), dim3(CT),
                                   args, 0, stream);
    }

    // Layer 1 GEMM
    gemm_mfma<IN_DIM><<<NB_G, 256, 0, stream>>>(feat, W1, H1);

    // agg(layer1) fused with gemm(layer2)
    agg1_gemm2<<<NB_F, 1024, 0, stream>>>(H1, dinv, b1, off, csr_src, W2, H2);

    // Final aggregate + bias + relu
    agg_csr<<<NB_W, 256, 0, stream>>>(H2, dinv, b2, off, csr_src, out);
}

// Round 13
// 157.440 us; speedup vs baseline: 2.1146x; 2.1146x over previous
//
#include <hip/hip_runtime.h>
#include <hip/hip_bf16.h>

#define N_NODES 50000
#define N_EDGES 800000
#define IN_DIM  256
#define OUT_DIM 64
#define CHUNKE  4096   // edges per radix chunk
#define NCHK    196    // ceil(800000/4096)
#define NBKT    196    // node buckets of 256 (196*256 = 50176 >= 50000)
#define STAGE   12288  // LDS-staged CSR slice (ints); avg bucket = 4081

using bf16x8 = __attribute__((ext_vector_type(8))) __bf16;
using f32x4  = __attribute__((ext_vector_type(4))) float;
using u32x4  = __attribute__((ext_vector_type(4))) unsigned int;

// ---------------------------------------------------------------------------
// Edge dtype probe (int64 vs int32), block-uniform; call with 256 threads.
// ---------------------------------------------------------------------------
__device__ __forceinline__ int probe_is64(const void* edges, int* nz_s) {
    if (threadIdx.x == 0) *nz_s = 0;
    __syncthreads();
    if (((const unsigned int*)edges)[2 * threadIdx.x + 1] != 0u) *nz_s = 1;
    __syncthreads();
    return (*nz_s == 0);
}

// ---------------------------------------------------------------------------
// R1: normalize edges + per-chunk 256-bin histogram (bin = dst>>8).
// ---------------------------------------------------------------------------
__global__ __launch_bounds__(256) void radix_hist(const void* __restrict__ edges,
                                                  int* __restrict__ src32,
                                                  int* __restrict__ dst32,
                                                  int* __restrict__ hist) {
    __shared__ int nz;
    __shared__ int h[256];
    int is64 = probe_is64(edges, &nz);
    h[threadIdx.x] = 0;
    __syncthreads();
    const int base = blockIdx.x * CHUNKE;
    for (int i = threadIdx.x; i < CHUNKE; i += 256) {
        int e = base + i;
        if (e < N_EDGES) {
            int s, d;
            if (is64) {
                s = (int)((const long long*)edges)[e];
                d = (int)((const long long*)edges)[(long long)N_EDGES + e];
            } else {
                s = ((const int*)edges)[e];
                d = ((const int*)edges)[(long long)N_EDGES + e];
            }
            src32[e] = s;
            dst32[e] = d;
            atomicAdd(&h[d >> 8], 1);
        }
    }
    __syncthreads();
    hist[blockIdx.x * 256 + threadIdx.x] = h[threadIdx.x];
}

// ---------------------------------------------------------------------------
// R2: per-bin exclusive scan over chunks (in place); bsum[b] = bin total.
// One wave per bin; 4 segments of 64 chunks with carried wave-scan.
// ---------------------------------------------------------------------------
__global__ __launch_bounds__(64) void radix_scan(int* __restrict__ hist,
                                                 int* __restrict__ bsum) {
    const int b = blockIdx.x, l = threadIdx.x;
    int carry = 0;
#pragma unroll
    for (int seg = 0; seg < 4; ++seg) {
        int c = seg * 64 + l;
        int v = (c < NCHK) ? hist[c * 256 + b] : 0;
        int incl = v;
        for (int s = 1; s < 64; s <<= 1) {
            int t = __shfl_up(incl, s);
            if (l >= s) incl += t;
        }
        if (c < NCHK) hist[c * 256 + b] = incl - v + carry;
        carry += __shfl(incl, 63);
    }
    if (l == 0) bsum[b] = carry;
}

// R3: exclusive scan of 256 bin totals -> bbase[257] (bbase[256] = N_EDGES).
__global__ void bsum_scan(const int* __restrict__ bsum, int* __restrict__ bbase) {
    __shared__ int sm[256];
    int t = threadIdx.x;
    int v = bsum[t];
    sm[t] = v;
    __syncthreads();
    for (int s = 1; s < 256; s <<= 1) {
        int tv = 0;
        if (t >= s) tv = sm[t - s];
        __syncthreads();
        if (t >= s) sm[t] += tv;
        __syncthreads();
    }
    bbase[t] = sm[t] - v;
    if (t == 255) bbase[256] = sm[255];
}

// ---------------------------------------------------------------------------
// R4: scatter edges to bucket-sorted COO (dense-ish writes: ~21 edges/bin
// per chunk land contiguously at bbase[bin] + chunkbase + local).
// ---------------------------------------------------------------------------
__global__ __launch_bounds__(256) void radix_scatter(const int* __restrict__ src32,
                                                     const int* __restrict__ dst32,
                                                     const int* __restrict__ hist,
                                                     const int* __restrict__ bbase,
                                                     int2* __restrict__ ebuf) {
    __shared__ int lcur[256];
    lcur[threadIdx.x] = 0;
    __syncthreads();
    const int base = blockIdx.x * CHUNKE;
    for (int i = threadIdx.x; i < CHUNKE; i += 256) {
        int e = base + i;
        if (e < N_EDGES) {
            int s = src32[e], d = dst32[e];
            int bin = d >> 8;
            int loc = atomicAdd(&lcur[bin], 1);
            int pos = bbase[bin] + hist[blockIdx.x * 256 + bin] + loc;
            ebuf[pos] = make_int2(s, d);
        }
    }
}

// ---------------------------------------------------------------------------
// R5: per-bucket finalize: node histogram -> off/dinv (bbase[b] is the CSR
// base!), then build the bucket's CSR slice in LDS and write it coalesced.
// ---------------------------------------------------------------------------
__global__ __launch_bounds__(256) void bucket_finalize(const int2* __restrict__ ebuf,
                                                       const int* __restrict__ bbase,
                                                       float* __restrict__ dinv,
                                                       int* __restrict__ off,
                                                       int* __restrict__ csr_src) {
    __shared__ int hist[256];
    __shared__ int sm[256];
    __shared__ int cur[256];
    __shared__ int stage[STAGE];
    const int b = blockIdx.x, t = threadIdx.x;
    const int beg = bbase[b], end = bbase[b + 1], size = end - beg;

    hist[t] = 0;
    __syncthreads();
    for (int e = beg + t; e < end; e += 256) atomicAdd(&hist[ebuf[e].y & 255], 1);
    __syncthreads();

    int v = hist[t];
    sm[t] = v;
    __syncthreads();
    for (int s = 1; s < 256; s <<= 1) {
        int tv = 0;
        if (t >= s) tv = sm[t - s];
        __syncthreads();
        if (t >= s) sm[t] += tv;
        __syncthreads();
    }
    int pre = sm[t] - v;   // exclusive prefix within bucket

    int node = b * 256 + t;
    if (node < N_NODES) {
        off[node] = beg + pre;
        dinv[node] = rsqrtf((float)(v + 1));
    }
    if (b == NBKT - 1 && t == 0) off[N_NODES] = end;

    cur[t] = pre;
    __syncthreads();

    if (size <= STAGE) {
        for (int e = beg + t; e < end; e += 256) {
            int2 ed = ebuf[e];
            int p = atomicAdd(&cur[ed.y & 255], 1);
            stage[p] = ed.x;
        }
        __syncthreads();
        for (int i = t; i < size; i += 256) csr_src[beg + i] = stage[i];
    } else {  // safety fallback (never for random input)
        for (int e = beg + t; e < end; e += 256) {
            int2 ed = ebuf[e];
            int p = atomicAdd(&cur[ed.y & 255], 1);
            csr_src[beg + p] = ed.x;
        }
    }
}

// ---------------------------------------------------------------------------
// MFMA split-bf16 GEMM (truncation split, 3 MFMA, rel err ~2^-16). Unchanged.
// ---------------------------------------------------------------------------
union BFu { u32x4 u; bf16x8 b; };

__device__ __forceinline__ void split_pack(float x0, float x1,
                                           unsigned& hi, unsigned& lo) {
    unsigned u0 = __float_as_uint(x0), u1 = __float_as_uint(x1);
    hi = (u1 & 0xFFFF0000u) | (u0 >> 16);
    float h0 = __uint_as_float(u0 & 0xFFFF0000u);
    float h1 = __uint_as_float(u1 & 0xFFFF0000u);
    unsigned r0 = __float_as_uint(x0 - h0);
    unsigned r1 = __float_as_uint(x1 - h1);
    lo = (r1 & 0xFFFF0000u) | (r0 >> 16);
}

template <int K>
__device__ __forceinline__ void gemm_body(int gbid, const float* __restrict__ X,
                                          const float* __restrict__ W,
                                          float* __restrict__ H) {
    constexpr int NS = K / 32;
    const int lane = threadIdx.x & 63;
    const int wave = threadIdx.x >> 6;
    const int lm   = lane & 15;
    const int kg   = lane >> 4;

    BFu bhi[NS], blo[NS];
#pragma unroll
    for (int s = 0; s < NS; ++s) {
#pragma unroll
        for (int jp = 0; jp < 4; ++jp) {
            float w0 = W[(size_t)(s * 32 + kg * 8 + 2 * jp)     * 64 + wave * 16 + lm];
            float w1 = W[(size_t)(s * 32 + kg * 8 + 2 * jp + 1) * 64 + wave * 16 + lm];
            unsigned h, l;
            split_pack(w0, w1, h, l);
            bhi[s].u[jp] = h;
            blo[s].u[jp] = l;
        }
    }

    const int r0 = gbid * 64;
    const float* xr[4];
#pragma unroll
    for (int m = 0; m < 4; ++m) {
        int r = r0 + m * 16 + lm;
        xr[m] = X + (size_t)((r < N_NODES) ? r : (N_NODES - 1)) * K;
    }

    f32x4 acc[4] = {};

#pragma unroll
    for (int s = 0; s < NS; ++s) {
#pragma unroll
        for (int m = 0; m < 4; ++m) {
            float4 a0 = *(const float4*)(xr[m] + s * 32 + kg * 8);
            float4 a1 = *(const float4*)(xr[m] + s * 32 + kg * 8 + 4);
            BFu ah, al;
            unsigned h, l;
            split_pack(a0.x, a0.y, h, l); ah.u[0] = h; al.u[0] = l;
            split_pack(a0.z, a0.w, h, l); ah.u[1] = h; al.u[1] = l;
            split_pack(a1.x, a1.y, h, l); ah.u[2] = h; al.u[2] = l;
            split_pack(a1.z, a1.w, h, l); ah.u[3] = h; al.u[3] = l;
            acc[m] = __builtin_amdgcn_mfma_f32_16x16x32_bf16(ah.b, bhi[s].b, acc[m], 0, 0, 0);
            acc[m] = __builtin_amdgcn_mfma_f32_16x16x32_bf16(ah.b, blo[s].b, acc[m], 0, 0, 0);
            acc[m] = __builtin_amdgcn_mfma_f32_16x16x32_bf16(al.b, bhi[s].b, acc[m], 0, 0, 0);
        }
    }

    const int c = wave * 16 + lm;
#pragma unroll
    for (int m = 0; m < 4; ++m) {
#pragma unroll
        for (int t = 0; t < 4; ++t) {
            int r = r0 + m * 16 + kg * 4 + t;
            if (r < N_NODES) H[(size_t)r * 64 + c] = acc[m][t];
        }
    }
}

template <int K>
__global__ __launch_bounds__(256) void gemm_mfma(const float* __restrict__ X,
                                                 const float* __restrict__ W,
                                                 float* __restrict__ H) {
    gemm_body<K>((int)blockIdx.x, X, W, H);
}

// ---------------------------------------------------------------------------
// Gather-aggregate: one wave per dst node, lane = column. Unchanged.
// out = relu( (Σ_s H[s]*dinv[s] + H[d]*dd) * dd + b )
// ---------------------------------------------------------------------------
__global__ __launch_bounds__(256) void agg_csr(const float* __restrict__ H,
                                               const float* __restrict__ dinv,
                                               const float* __restrict__ b,
                                               const int* __restrict__ off,
                                               const int* __restrict__ csr_src,
                                               float* __restrict__ out) {
    int wid  = (blockIdx.x * 256 + threadIdx.x) >> 6;
    int lane = threadIdx.x & 63;
    if (wid >= N_NODES) return;
    float dd = dinv[wid];
    float acc = H[(size_t)wid * 64 + lane] * dd;
    int beg = off[wid], end = off[wid + 1];
    for (int k0 = beg; k0 < end; k0 += 64) {
        int myk = k0 + lane;
        int   s_l  = (myk < end) ? csr_src[myk] : 0;
        float ds_l = (myk < end) ? dinv[s_l] : 0.f;
        int cnt = min(64, end - k0);
        int i = 0;
        for (; i + 8 <= cnt; i += 8) {
            float v[8], nm[8];
#pragma unroll
            for (int jj = 0; jj < 8; ++jj) {
                int s  = __shfl(s_l, i + jj);
                nm[jj] = __shfl(ds_l, i + jj);
                v[jj]  = H[(size_t)s * 64 + lane];
            }
#pragma unroll
            for (int jj = 0; jj < 8; ++jj) acc = fmaf(v[jj], nm[jj], acc);
        }
        for (; i < cnt; ++i) {
            int   s  = __shfl(s_l, i);
            float nm = __shfl(ds_l, i);
            acc = fmaf(H[(size_t)s * 64 + lane], nm, acc);
        }
    }
    out[(size_t)wid * 64 + lane] = fmaxf(fmaf(acc, dd, b[lane]), 0.f);
}

extern "C" void kernel_launch(void* const* d_in, const int* in_sizes, int n_in,
                              void* d_out, int out_size, void* d_ws, size_t ws_size,
                              hipStream_t stream) {
    const float* feat = (const float*)d_in[0];
    const float* W1   = (const float*)d_in[1];
    const float* b1   = (const float*)d_in[2];
    const float* W2   = (const float*)d_in[3];
    const float* b2   = (const float*)d_in[4];
    const void*  edges = d_in[5];
    float* out = (float*)d_out;

    char* ws = (char*)d_ws;
    const size_t SZ_E = (size_t)N_EDGES * 4;
    int*   bbase   = (int*)ws;                                   // 257 ints
    int*   bsum    = (int*)(ws + 2048);                          // 256 ints
    int*   hist    = (int*)(ws + 4096);                          // 196*256 ints (~200 KB)
    float* dinv    = (float*)(ws + 4096 + 204800);               // 50000 f32
    int*   off     = (int*)(ws + 4096 + 204800 + 204800);        // 50001 ints
    size_t o = 4096 + 3 * 204800;
    int*   src32   = (int*)(ws + o);              o += SZ_E;     // 3.2 MB
    int*   dst32   = (int*)(ws + o);              o += SZ_E;     // 3.2 MB
    int2*  ebuf    = (int2*)(ws + o);             o += 2 * SZ_E; // 6.4 MB
    int*   csr_src = (int*)(ws + o);              o += SZ_E;     // 3.2 MB
    float* H       = (float*)(ws + o);                           // 12.8 MB

    const int NB_G = (N_NODES + 63) / 64;         // 782
    const int NB_W = (N_NODES * 64 + 255) / 256;  // 12500

    // Preprocessing: LDS-binned counting sort (no global returning atomics,
    // no line-amplified random writes), off/dinv derived from bucket bases.
    radix_hist<<<NCHK, 256, 0, stream>>>(edges, src32, dst32, hist);
    radix_scan<<<256, 64, 0, stream>>>(hist, bsum);
    bsum_scan<<<1, 256, 0, stream>>>(bsum, bbase);
    radix_scatter<<<NCHK, 256, 0, stream>>>(src32, dst32, hist, bbase, ebuf);
    bucket_finalize<<<NBKT, 256, 0, stream>>>(ebuf, bbase, dinv, off, csr_src);

    // Layer 1
    gemm_mfma<IN_DIM><<<NB_G, 256, 0, stream>>>(feat, W1, H);
    agg_csr<<<NB_W, 256, 0, stream>>>(H, dinv, b1, off, csr_src, out);

    // Layer 2 (out holds relu'd z1; H reused)
    gemm_mfma<OUT_DIM><<<NB_G, 256, 0, stream>>>(out, W2, H);
    agg_csr<<<NB_W, 256, 0, stream>>>(H, dinv, b2, off, csr_src, out);
}

// Round 14
// 147.834 us; speedup vs baseline: 2.2520x; 1.0650x over previous
//
#include <hip/hip_runtime.h>
#include <hip/hip_bf16.h>

#define N_NODES 50000
#define N_EDGES 800000
#define IN_DIM  256
#define OUT_DIM 64
#define CHUNKE  4096   // edges per radix chunk
#define NCHK    196    // ceil(800000/4096)
#define NBKT    196    // node buckets of 256 (196*256 = 50176 >= 50000)
#define STAGE   12288  // LDS-staged CSR slice (ints); avg bucket = 4081

using bf16x8 = __attribute__((ext_vector_type(8))) __bf16;
using f32x4  = __attribute__((ext_vector_type(4))) float;
using u32x4  = __attribute__((ext_vector_type(4))) unsigned int;

// ---------------------------------------------------------------------------
// MFMA split-bf16 GEMM (truncation split, 3 MFMA, rel err ~2^-16).
// ---------------------------------------------------------------------------
union BFu { u32x4 u; bf16x8 b; };

__device__ __forceinline__ void split_pack(float x0, float x1,
                                           unsigned& hi, unsigned& lo) {
    unsigned u0 = __float_as_uint(x0), u1 = __float_as_uint(x1);
    hi = (u1 & 0xFFFF0000u) | (u0 >> 16);
    float h0 = __uint_as_float(u0 & 0xFFFF0000u);
    float h1 = __uint_as_float(u1 & 0xFFFF0000u);
    unsigned r0 = __float_as_uint(x0 - h0);
    unsigned r1 = __float_as_uint(x1 - h1);
    lo = (r1 & 0xFFFF0000u) | (r0 >> 16);
}

template <int K>
__device__ __forceinline__ void gemm_body(int gbid, const float* __restrict__ X,
                                          const float* __restrict__ W,
                                          float* __restrict__ H) {
    constexpr int NS = K / 32;
    const int lane = threadIdx.x & 63;
    const int wave = threadIdx.x >> 6;
    const int lm   = lane & 15;
    const int kg   = lane >> 4;

    BFu bhi[NS], blo[NS];
#pragma unroll
    for (int s = 0; s < NS; ++s) {
#pragma unroll
        for (int jp = 0; jp < 4; ++jp) {
            float w0 = W[(size_t)(s * 32 + kg * 8 + 2 * jp)     * 64 + wave * 16 + lm];
            float w1 = W[(size_t)(s * 32 + kg * 8 + 2 * jp + 1) * 64 + wave * 16 + lm];
            unsigned h, l;
            split_pack(w0, w1, h, l);
            bhi[s].u[jp] = h;
            blo[s].u[jp] = l;
        }
    }

    const int r0 = gbid * 64;
    const float* xr[4];
#pragma unroll
    for (int m = 0; m < 4; ++m) {
        int r = r0 + m * 16 + lm;
        xr[m] = X + (size_t)((r < N_NODES) ? r : (N_NODES - 1)) * K;
    }

    f32x4 acc[4] = {};

#pragma unroll
    for (int s = 0; s < NS; ++s) {
#pragma unroll
        for (int m = 0; m < 4; ++m) {
            float4 a0 = *(const float4*)(xr[m] + s * 32 + kg * 8);
            float4 a1 = *(const float4*)(xr[m] + s * 32 + kg * 8 + 4);
            BFu ah, al;
            unsigned h, l;
            split_pack(a0.x, a0.y, h, l); ah.u[0] = h; al.u[0] = l;
            split_pack(a0.z, a0.w, h, l); ah.u[1] = h; al.u[1] = l;
            split_pack(a1.x, a1.y, h, l); ah.u[2] = h; al.u[2] = l;
            split_pack(a1.z, a1.w, h, l); ah.u[3] = h; al.u[3] = l;
            acc[m] = __builtin_amdgcn_mfma_f32_16x16x32_bf16(ah.b, bhi[s].b, acc[m], 0, 0, 0);
            acc[m] = __builtin_amdgcn_mfma_f32_16x16x32_bf16(ah.b, blo[s].b, acc[m], 0, 0, 0);
            acc[m] = __builtin_amdgcn_mfma_f32_16x16x32_bf16(al.b, bhi[s].b, acc[m], 0, 0, 0);
        }
    }

    const int c = wave * 16 + lm;
#pragma unroll
    for (int m = 0; m < 4; ++m) {
#pragma unroll
        for (int t = 0; t < 4; ++t) {
            int r = r0 + m * 16 + kg * 4 + t;
            if (r < N_NODES) H[(size_t)r * 64 + c] = acc[m][t];
        }
    }
}

// ---------------------------------------------------------------------------
// Fused R1 + layer-1 GEMM (disjoint block ranges; both read-dominated).
// Blocks [0,NCHK): normalize edges + per-chunk 256-bin histogram (bin=dst>>8).
// Blocks [NCHK, NCHK+782): H1 = feat @ W1 (MFMA).
// ---------------------------------------------------------------------------
template <int K>
__global__ __launch_bounds__(256) void fused_hist_gemm1(const void* __restrict__ edges,
                                                        int* __restrict__ src32,
                                                        int* __restrict__ dst32,
                                                        int* __restrict__ hist,
                                                        const float* __restrict__ X,
                                                        const float* __restrict__ W,
                                                        float* __restrict__ H) {
    if ((int)blockIdx.x < NCHK) {
        __shared__ int nz;
        __shared__ int h[256];
        if (threadIdx.x == 0) nz = 0;
        h[threadIdx.x] = 0;
        __syncthreads();
        if (((const unsigned int*)edges)[2 * threadIdx.x + 1] != 0u) nz = 1;
        __syncthreads();
        const int is64 = (nz == 0);
        const int base = blockIdx.x * CHUNKE;
        for (int i = threadIdx.x; i < CHUNKE; i += 256) {
            int e = base + i;
            if (e < N_EDGES) {
                int s, d;
                if (is64) {
                    s = (int)((const long long*)edges)[e];
                    d = (int)((const long long*)edges)[(long long)N_EDGES + e];
                } else {
                    s = ((const int*)edges)[e];
                    d = ((const int*)edges)[(long long)N_EDGES + e];
                }
                src32[e] = s;
                dst32[e] = d;
                atomicAdd(&h[d >> 8], 1);
            }
        }
        __syncthreads();
        hist[blockIdx.x * 256 + threadIdx.x] = h[threadIdx.x];
    } else {
        gemm_body<K>((int)blockIdx.x - NCHK, X, W, H);
    }
}

// ---------------------------------------------------------------------------
// R2: per-bin exclusive scan over chunks (in place); bsum[b] = bin total.
// ---------------------------------------------------------------------------
__global__ __launch_bounds__(64) void radix_scan(int* __restrict__ hist,
                                                 int* __restrict__ bsum) {
    const int b = blockIdx.x, l = threadIdx.x;
    int carry = 0;
#pragma unroll
    for (int seg = 0; seg < 4; ++seg) {
        int c = seg * 64 + l;
        int v = (c < NCHK) ? hist[c * 256 + b] : 0;
        int incl = v;
        for (int s = 1; s < 64; s <<= 1) {
            int t = __shfl_up(incl, s);
            if (l >= s) incl += t;
        }
        if (c < NCHK) hist[c * 256 + b] = incl - v + carry;
        carry += __shfl(incl, 63);
    }
    if (l == 0) bsum[b] = carry;
}

// ---------------------------------------------------------------------------
// R4: scatter to bucket-sorted COO. Bucket bases derived from bsum by an
// in-LDS 256-scan (replaces the bsum_scan dispatch).
// ---------------------------------------------------------------------------
__global__ __launch_bounds__(256) void radix_scatter(const int* __restrict__ src32,
                                                     const int* __restrict__ dst32,
                                                     const int* __restrict__ hist,
                                                     const int* __restrict__ bsum,
                                                     int2* __restrict__ ebuf) {
    __shared__ int lcur[256];
    __shared__ int sm[256];
    __shared__ int sbase[256];
    const int t = threadIdx.x;
    int v = bsum[t];
    sm[t] = v;
    lcur[t] = 0;
    __syncthreads();
    for (int s = 1; s < 256; s <<= 1) {
        int tv = 0;
        if (t >= s) tv = sm[t - s];
        __syncthreads();
        if (t >= s) sm[t] += tv;
        __syncthreads();
    }
    sbase[t] = sm[t] - v;
    __syncthreads();
    const int base = blockIdx.x * CHUNKE;
    for (int i = t; i < CHUNKE; i += 256) {
        int e = base + i;
        if (e < N_EDGES) {
            int s = src32[e], d = dst32[e];
            int bin = d >> 8;
            int loc = atomicAdd(&lcur[bin], 1);
            int pos = sbase[bin] + hist[blockIdx.x * 256 + bin] + loc;
            ebuf[pos] = make_int2(s, d);
        }
    }
}

// ---------------------------------------------------------------------------
// R5: per-bucket finalize (bucket base via in-LDS bsum scan): node hist ->
// off/dinv, then CSR slice staged in LDS, written coalesced.
// ---------------------------------------------------------------------------
__global__ __launch_bounds__(256) void bucket_finalize(const int2* __restrict__ ebuf,
                                                       const int* __restrict__ bsum,
                                                       float* __restrict__ dinv,
                                                       int* __restrict__ off,
                                                       int* __restrict__ csr_src) {
    __shared__ int hist[256];
    __shared__ int sm[256];
    __shared__ int cur[256];
    __shared__ int stage[STAGE];
    __shared__ int beg_s, end_s;
    const int b = blockIdx.x, t = threadIdx.x;

    // bucket base from bsum
    int v = bsum[t];
    sm[t] = v;
    __syncthreads();
    for (int s = 1; s < 256; s <<= 1) {
        int tv = 0;
        if (t >= s) tv = sm[t - s];
        __syncthreads();
        if (t >= s) sm[t] += tv;
        __syncthreads();
    }
    if (t == b) { beg_s = sm[t] - v; end_s = sm[t]; }
    __syncthreads();
    const int beg = beg_s, end = end_s, size = end - beg;

    hist[t] = 0;
    __syncthreads();
    for (int e = beg + t; e < end; e += 256) atomicAdd(&hist[ebuf[e].y & 255], 1);
    __syncthreads();

    v = hist[t];
    sm[t] = v;
    __syncthreads();
    for (int s = 1; s < 256; s <<= 1) {
        int tv = 0;
        if (t >= s) tv = sm[t - s];
        __syncthreads();
        if (t >= s) sm[t] += tv;
        __syncthreads();
    }
    int pre = sm[t] - v;   // exclusive prefix within bucket

    int node = b * 256 + t;
    if (node < N_NODES) {
        off[node] = beg + pre;
        dinv[node] = rsqrtf((float)(v + 1));
    }
    if (b == NBKT - 1 && t == 0) off[N_NODES] = end;

    cur[t] = pre;
    __syncthreads();

    if (size <= STAGE) {
        for (int e = beg + t; e < end; e += 256) {
            int2 ed = ebuf[e];
            int p = atomicAdd(&cur[ed.y & 255], 1);
            stage[p] = ed.x;
        }
        __syncthreads();
        for (int i = t; i < size; i += 256) csr_src[beg + i] = stage[i];
    } else {  // safety fallback
        for (int e = beg + t; e < end; e += 256) {
            int2 ed = ebuf[e];
            int p = atomicAdd(&cur[ed.y & 255], 1);
            csr_src[beg + p] = ed.x;
        }
    }
}

template <int K>
__global__ __launch_bounds__(256) void gemm_mfma(const float* __restrict__ X,
                                                 const float* __restrict__ W,
                                                 float* __restrict__ H) {
    gemm_body<K>((int)blockIdx.x, X, W, H);
}

// ---------------------------------------------------------------------------
// Gather-aggregate: one wave per dst node, lane = column.
// out = relu( (Σ_s H[s]*dinv[s] + H[d]*dd) * dd + b )
// ---------------------------------------------------------------------------
__global__ __launch_bounds__(256) void agg_csr(const float* __restrict__ H,
                                               const float* __restrict__ dinv,
                                               const float* __restrict__ b,
                                               const int* __restrict__ off,
                                               const int* __restrict__ csr_src,
                                               float* __restrict__ out) {
    int wid  = (blockIdx.x * 256 + threadIdx.x) >> 6;
    int lane = threadIdx.x & 63;
    if (wid >= N_NODES) return;
    float dd = dinv[wid];
    float acc = H[(size_t)wid * 64 + lane] * dd;
    int beg = off[wid], end = off[wid + 1];
    for (int k0 = beg; k0 < end; k0 += 64) {
        int myk = k0 + lane;
        int   s_l  = (myk < end) ? csr_src[myk] : 0;
        float ds_l = (myk < end) ? dinv[s_l] : 0.f;
        int cnt = min(64, end - k0);
        int i = 0;
        for (; i + 8 <= cnt; i += 8) {
            float v[8], nm[8];
#pragma unroll
            for (int jj = 0; jj < 8; ++jj) {
                int s  = __shfl(s_l, i + jj);
                nm[jj] = __shfl(ds_l, i + jj);
                v[jj]  = H[(size_t)s * 64 + lane];
            }
#pragma unroll
            for (int jj = 0; jj < 8; ++jj) acc = fmaf(v[jj], nm[jj], acc);
        }
        for (; i < cnt; ++i) {
            int   s  = __shfl(s_l, i);
            float nm = __shfl(ds_l, i);
            acc = fmaf(H[(size_t)s * 64 + lane], nm, acc);
        }
    }
    out[(size_t)wid * 64 + lane] = fmaxf(fmaf(acc, dd, b[lane]), 0.f);
}

extern "C" void kernel_launch(void* const* d_in, const int* in_sizes, int n_in,
                              void* d_out, int out_size, void* d_ws, size_t ws_size,
                              hipStream_t stream) {
    const float* feat = (const float*)d_in[0];
    const float* W1   = (const float*)d_in[1];
    const float* b1   = (const float*)d_in[2];
    const float* W2   = (const float*)d_in[3];
    const float* b2   = (const float*)d_in[4];
    const void*  edges = d_in[5];
    float* out = (float*)d_out;

    char* ws = (char*)d_ws;
    const size_t SZ_E = (size_t)N_EDGES * 4;
    int*   bsum    = (int*)(ws + 2048);                          // 256 ints
    int*   hist    = (int*)(ws + 4096);                          // 196*256 ints
    float* dinv    = (float*)(ws + 4096 + 204800);               // 50000 f32
    int*   off     = (int*)(ws + 4096 + 204800 + 204800);        // 50001 ints
    size_t o = 4096 + 3 * 204800;
    int*   src32   = (int*)(ws + o);              o += SZ_E;     // 3.2 MB
    int*   dst32   = (int*)(ws + o);              o += SZ_E;     // 3.2 MB
    int2*  ebuf    = (int2*)(ws + o);             o += 2 * SZ_E; // 6.4 MB
    int*   csr_src = (int*)(ws + o);              o += SZ_E;     // 3.2 MB
    float* H       = (float*)(ws + o);                           // 12.8 MB

    const int NB_G = (N_NODES + 63) / 64;         // 782
    const int NB_W = (N_NODES * 64 + 255) / 256;  // 12500

    // R1 + layer-1 GEMM fused (hist hides under gemm1).
    fused_hist_gemm1<IN_DIM><<<NCHK + NB_G, 256, 0, stream>>>(
        edges, src32, dst32, hist, feat, W1, H);
    radix_scan<<<256, 64, 0, stream>>>(hist, bsum);
    radix_scatter<<<NCHK, 256, 0, stream>>>(src32, dst32, hist, bsum, ebuf);
    bucket_finalize<<<NBKT, 256, 0, stream>>>(ebuf, bsum, dinv, off, csr_src);

    // Layer 1 aggregate (H1 ready since fused kernel).
    agg_csr<<<NB_W, 256, 0, stream>>>(H, dinv, b1, off, csr_src, out);

    // Layer 2 (out holds relu'd z1; H reused)
    gemm_mfma<OUT_DIM><<<NB_G, 256, 0, stream>>>(out, W2, H);
    agg_csr<<<NB_W, 256, 0, stream>>>(H, dinv, b2, off, csr_src, out);
}

// Round 15
// 124.058 us; speedup vs baseline: 2.6837x; 1.1917x over previous
//
#include <hip/hip_runtime.h>
#include <hip/hip_bf16.h>

#define N_NODES 50000
#define N_EDGES 800000
#define IN_DIM  256
#define OUT_DIM 64
#define CHUNKE  4096   // edges per radix chunk
#define NCHK    196    // ceil(800000/4096)
#define NBKT    196    // node buckets of 256
#define STAGE   12288  // LDS-staged CSR slice (ints)

using bf16x8 = __attribute__((ext_vector_type(8))) __bf16;
using f32x4  = __attribute__((ext_vector_type(4))) float;
using u32x4  = __attribute__((ext_vector_type(4))) unsigned int;

// ---------------------------------------------------------------------------
// MFMA split-bf16 GEMM (truncation split, 3 MFMA, rel err ~2^-16).
// A staged in LDS per block (shared by all 4 waves; kills the 4x duplicate
// A-loads + scattered-line L1 pattern of r9..r14).
// ---------------------------------------------------------------------------
union BFu { u32x4 u; bf16x8 b; };

__device__ __forceinline__ void split_pack(float x0, float x1,
                                           unsigned& hi, unsigned& lo) {
    unsigned u0 = __float_as_uint(x0), u1 = __float_as_uint(x1);
    hi = (u1 & 0xFFFF0000u) | (u0 >> 16);
    float h0 = __uint_as_float(u0 & 0xFFFF0000u);
    float h1 = __uint_as_float(u1 & 0xFFFF0000u);
    unsigned r0 = __float_as_uint(x0 - h0);
    unsigned r1 = __float_as_uint(x1 - h1);
    lo = (r1 & 0xFFFF0000u) | (r0 >> 16);
}

// lds: 8192 B = a_hi[64][32]bf16 + a_lo[64][32]bf16
template <int K>
__device__ __forceinline__ void gemm_body(int gbid, const float* __restrict__ X,
                                          const float* __restrict__ W,
                                          float* __restrict__ H,
                                          char* lds) {
    constexpr int NS = K / 32;
    unsigned short* a_hi = (unsigned short*)lds;
    unsigned short* a_lo = a_hi + 64 * 32;

    const int lane = threadIdx.x & 63;
    const int wave = threadIdx.x >> 6;   // output col tile 0..3
    const int lm   = lane & 15;
    const int kg   = lane >> 4;          // 0..3

    // B fragments (this wave's 16 cols), hi/lo, registers (static-indexed).
    BFu bhi[NS], blo[NS];
#pragma unroll
    for (int s = 0; s < NS; ++s) {
#pragma unroll
        for (int jp = 0; jp < 4; ++jp) {
            float w0 = W[(size_t)(s * 32 + kg * 8 + 2 * jp)     * 64 + wave * 16 + lm];
            float w1 = W[(size_t)(s * 32 + kg * 8 + 2 * jp + 1) * 64 + wave * 16 + lm];
            unsigned h, l;
            split_pack(w0, w1, h, l);
            bhi[s].u[jp] = h;
            blo[s].u[jp] = l;
        }
    }

    // Staging role: thread t stages row t>>2, k-offset (t&3)*8 (coalesced).
    const int srow = threadIdx.x >> 2;
    const int skc  = (threadIdx.x & 3) * 8;
    int gr = gbid * 64 + srow;
    const float* xs = X + (size_t)((gr < N_NODES) ? gr : (N_NODES - 1)) * K;

    f32x4 acc[4] = {};

#pragma unroll
    for (int s = 0; s < NS; ++s) {
        float4 c0 = *(const float4*)(xs + s * 32 + skc);
        float4 c1 = *(const float4*)(xs + s * 32 + skc + 4);
        BFu h_, l_;
        unsigned h, l;
        split_pack(c0.x, c0.y, h, l); h_.u[0] = h; l_.u[0] = l;
        split_pack(c0.z, c0.w, h, l); h_.u[1] = h; l_.u[1] = l;
        split_pack(c1.x, c1.y, h, l); h_.u[2] = h; l_.u[2] = l;
        split_pack(c1.z, c1.w, h, l); h_.u[3] = h; l_.u[3] = l;
        __syncthreads();                       // prior chunk's reads done
        *(u32x4*)(a_hi + srow * 32 + skc) = h_.u;
        *(u32x4*)(a_lo + srow * 32 + skc) = l_.u;
        __syncthreads();                       // writes visible
#pragma unroll
        for (int m = 0; m < 4; ++m) {
            BFu ah, al;
            ah.u = *(const u32x4*)(a_hi + (m * 16 + lm) * 32 + kg * 8);
            al.u = *(const u32x4*)(a_lo + (m * 16 + lm) * 32 + kg * 8);
            acc[m] = __builtin_amdgcn_mfma_f32_16x16x32_bf16(ah.b, bhi[s].b, acc[m], 0, 0, 0);
            acc[m] = __builtin_amdgcn_mfma_f32_16x16x32_bf16(ah.b, blo[s].b, acc[m], 0, 0, 0);
            acc[m] = __builtin_amdgcn_mfma_f32_16x16x32_bf16(al.b, bhi[s].b, acc[m], 0, 0, 0);
        }
    }

    const int c = wave * 16 + lm;
#pragma unroll
    for (int m = 0; m < 4; ++m) {
#pragma unroll
        for (int t = 0; t < 4; ++t) {
            int r = gbid * 64 + m * 16 + kg * 4 + t;
            if (r < N_NODES) H[(size_t)r * 64 + c] = acc[m][t];
        }
    }
}

// ---------------------------------------------------------------------------
// Fused R1 + layer-1 GEMM (disjoint block ranges).
// ---------------------------------------------------------------------------
template <int K>
__global__ __launch_bounds__(256) void fused_hist_gemm1(const void* __restrict__ edges,
                                                        int* __restrict__ src32,
                                                        int* __restrict__ dst32,
                                                        int* __restrict__ hist,
                                                        const float* __restrict__ X,
                                                        const float* __restrict__ W,
                                                        float* __restrict__ H) {
    __shared__ char lds[8192];
    if ((int)blockIdx.x < NCHK) {
        int* h  = (int*)lds;          // 256 ints
        int* nz = (int*)(lds + 1024);
        if (threadIdx.x == 0) *nz = 0;
        h[threadIdx.x] = 0;
        __syncthreads();
        if (((const unsigned int*)edges)[2 * threadIdx.x + 1] != 0u) *nz = 1;
        __syncthreads();
        const int is64 = (*nz == 0);
        const int base = blockIdx.x * CHUNKE;
        for (int i = threadIdx.x; i < CHUNKE; i += 256) {
            int e = base + i;
            if (e < N_EDGES) {
                int s, d;
                if (is64) {
                    s = (int)((const long long*)edges)[e];
                    d = (int)((const long long*)edges)[(long long)N_EDGES + e];
                } else {
                    s = ((const int*)edges)[e];
                    d = ((const int*)edges)[(long long)N_EDGES + e];
                }
                src32[e] = s;
                dst32[e] = d;
                atomicAdd(&h[d >> 8], 1);
            }
        }
        __syncthreads();
        hist[blockIdx.x * 256 + threadIdx.x] = h[threadIdx.x];
    } else {
        gemm_body<K>((int)blockIdx.x - NCHK, X, W, H, lds);
    }
}

// ---------------------------------------------------------------------------
// R2: per-bin exclusive scan over chunks (in place); bsum[b] = bin total.
// ---------------------------------------------------------------------------
__global__ __launch_bounds__(64) void radix_scan(int* __restrict__ hist,
                                                 int* __restrict__ bsum) {
    const int b = blockIdx.x, l = threadIdx.x;
    int carry = 0;
#pragma unroll
    for (int seg = 0; seg < 4; ++seg) {
        int c = seg * 64 + l;
        int v = (c < NCHK) ? hist[c * 256 + b] : 0;
        int incl = v;
        for (int s = 1; s < 64; s <<= 1) {
            int t = __shfl_up(incl, s);
            if (l >= s) incl += t;
        }
        if (c < NCHK) hist[c * 256 + b] = incl - v + carry;
        carry += __shfl(incl, 63);
    }
    if (l == 0) bsum[b] = carry;
}

// ---------------------------------------------------------------------------
// R4: scatter to bucket-sorted COO (bases via in-LDS scan of bsum).
// ---------------------------------------------------------------------------
__global__ __launch_bounds__(256) void radix_scatter(const int* __restrict__ src32,
                                                     const int* __restrict__ dst32,
                                                     const int* __restrict__ hist,
                                                     const int* __restrict__ bsum,
                                                     int2* __restrict__ ebuf) {
    __shared__ int lcur[256];
    __shared__ int sm[256];
    __shared__ int sbase[256];
    const int t = threadIdx.x;
    int v = bsum[t];
    sm[t] = v;
    lcur[t] = 0;
    __syncthreads();
    for (int s = 1; s < 256; s <<= 1) {
        int tv = 0;
        if (t >= s) tv = sm[t - s];
        __syncthreads();
        if (t >= s) sm[t] += tv;
        __syncthreads();
    }
    sbase[t] = sm[t] - v;
    __syncthreads();
    const int base = blockIdx.x * CHUNKE;
    for (int i = t; i < CHUNKE; i += 256) {
        int e = base + i;
        if (e < N_EDGES) {
            int s = src32[e], d = dst32[e];
            int bin = d >> 8;
            int loc = atomicAdd(&lcur[bin], 1);
            int pos = sbase[bin] + hist[blockIdx.x * 256 + bin] + loc;
            ebuf[pos] = make_int2(s, d);
        }
    }
}

// ---------------------------------------------------------------------------
// R5: per-bucket finalize: off/dinv + LDS-staged coalesced CSR slice.
// ---------------------------------------------------------------------------
__global__ __launch_bounds__(256) void bucket_finalize(const int2* __restrict__ ebuf,
                                                       const int* __restrict__ bsum,
                                                       float* __restrict__ dinv,
                                                       int* __restrict__ off,
                                                       int* __restrict__ csr_src) {
    __shared__ int hist[256];
    __shared__ int sm[256];
    __shared__ int cur[256];
    __shared__ int stage[STAGE];
    __shared__ int beg_s, end_s;
    const int b = blockIdx.x, t = threadIdx.x;

    int v = bsum[t];
    sm[t] = v;
    __syncthreads();
    for (int s = 1; s < 256; s <<= 1) {
        int tv = 0;
        if (t >= s) tv = sm[t - s];
        __syncthreads();
        if (t >= s) sm[t] += tv;
        __syncthreads();
    }
    if (t == b) { beg_s = sm[t] - v; end_s = sm[t]; }
    __syncthreads();
    const int beg = beg_s, end = end_s, size = end - beg;

    hist[t] = 0;
    __syncthreads();
    for (int e = beg + t; e < end; e += 256) atomicAdd(&hist[ebuf[e].y & 255], 1);
    __syncthreads();

    v = hist[t];
    sm[t] = v;
    __syncthreads();
    for (int s = 1; s < 256; s <<= 1) {
        int tv = 0;
        if (t >= s) tv = sm[t - s];
        __syncthreads();
        if (t >= s) sm[t] += tv;
        __syncthreads();
    }
    int pre = sm[t] - v;

    int node = b * 256 + t;
    if (node < N_NODES) {
        off[node] = beg + pre;
        dinv[node] = rsqrtf((float)(v + 1));
    }
    if (b == NBKT - 1 && t == 0) off[N_NODES] = end;

    cur[t] = pre;
    __syncthreads();

    if (size <= STAGE) {
        for (int e = beg + t; e < end; e += 256) {
            int2 ed = ebuf[e];
            int p = atomicAdd(&cur[ed.y & 255], 1);
            stage[p] = ed.x;
        }
        __syncthreads();
        for (int i = t; i < size; i += 256) csr_src[beg + i] = stage[i];
    } else {
        for (int e = beg + t; e < end; e += 256) {
            int2 ed = ebuf[e];
            int p = atomicAdd(&cur[ed.y & 255], 1);
            csr_src[beg + p] = ed.x;
        }
    }
}

template <int K>
__global__ __launch_bounds__(256) void gemm_mfma(const float* __restrict__ X,
                                                 const float* __restrict__ W,
                                                 float* __restrict__ H) {
    __shared__ char lds[8192];
    gemm_body<K>((int)blockIdx.x, X, W, H, lds);
}

// ---------------------------------------------------------------------------
// Gather-aggregate: one wave per dst node, lane = column.
// out = relu( (Σ_s H[s]*dinv[s] + H[d]*dd) * dd + b )
// ---------------------------------------------------------------------------
__global__ __launch_bounds__(256) void agg_csr(const float* __restrict__ H,
                                               const float* __restrict__ dinv,
                                               const float* __restrict__ b,
                                               const int* __restrict__ off,
                                               const int* __restrict__ csr_src,
                                               float* __restrict__ out) {
    int wid  = (blockIdx.x * 256 + threadIdx.x) >> 6;
    int lane = threadIdx.x & 63;
    if (wid >= N_NODES) return;
    float dd = dinv[wid];
    float acc = H[(size_t)wid * 64 + lane] * dd;
    int beg = off[wid], end = off[wid + 1];
    for (int k0 = beg; k0 < end; k0 += 64) {
        int myk = k0 + lane;
        int   s_l  = (myk < end) ? csr_src[myk] : 0;
        float ds_l = (myk < end) ? dinv[s_l] : 0.f;
        int cnt = min(64, end - k0);
        int i = 0;
        for (; i + 8 <= cnt; i += 8) {
            float v[8], nm[8];
#pragma unroll
            for (int jj = 0; jj < 8; ++jj) {
                int s  = __shfl(s_l, i + jj);
                nm[jj] = __shfl(ds_l, i + jj);
                v[jj]  = H[(size_t)s * 64 + lane];
            }
#pragma unroll
            for (int jj = 0; jj < 8; ++jj) acc = fmaf(v[jj], nm[jj], acc);
        }
        for (; i < cnt; ++i) {
            int   s  = __shfl(s_l, i);
            float nm = __shfl(ds_l, i);
            acc = fmaf(H[(size_t)s * 64 + lane], nm, acc);
        }
    }
    out[(size_t)wid * 64 + lane] = fmaxf(fmaf(acc, dd, b[lane]), 0.f);
}

extern "C" void kernel_launch(void* const* d_in, const int* in_sizes, int n_in,
                              void* d_out, int out_size, void* d_ws, size_t ws_size,
                              hipStream_t stream) {
    const float* feat = (const float*)d_in[0];
    const float* W1   = (const float*)d_in[1];
    const float* b1   = (const float*)d_in[2];
    const float* W2   = (const float*)d_in[3];
    const float* b2   = (const float*)d_in[4];
    const void*  edges = d_in[5];
    float* out = (float*)d_out;

    char* ws = (char*)d_ws;
    const size_t SZ_E = (size_t)N_EDGES * 4;
    int*   bsum    = (int*)(ws + 2048);                          // 256 ints
    int*   hist    = (int*)(ws + 4096);                          // 196*256 ints
    float* dinv    = (float*)(ws + 4096 + 204800);               // 50000 f32
    int*   off     = (int*)(ws + 4096 + 204800 + 204800);        // 50001 ints
    size_t o = 4096 + 3 * 204800;
    int*   src32   = (int*)(ws + o);              o += SZ_E;     // 3.2 MB
    int*   dst32   = (int*)(ws + o);              o += SZ_E;     // 3.2 MB
    int2*  ebuf    = (int2*)(ws + o);             o += 2 * SZ_E; // 6.4 MB
    int*   csr_src = (int*)(ws + o);              o += SZ_E;     // 3.2 MB
    float* H       = (float*)(ws + o);                           // 12.8 MB

    const int NB_G = (N_NODES + 63) / 64;         // 782
    const int NB_W = (N_NODES * 64 + 255) / 256;  // 12500

    // R1 + layer-1 GEMM fused (hist hides under gemm1).
    fused_hist_gemm1<IN_DIM><<<NCHK + NB_G, 256, 0, stream>>>(
        edges, src32, dst32, hist, feat, W1, H);
    radix_scan<<<256, 64, 0, stream>>>(hist, bsum);
    radix_scatter<<<NCHK, 256, 0, stream>>>(src32, dst32, hist, bsum, ebuf);
    bucket_finalize<<<NBKT, 256, 0, stream>>>(ebuf, bsum, dinv, off, csr_src);

    // Layer 1 aggregate.
    agg_csr<<<NB_W, 256, 0, stream>>>(H, dinv, b1, off, csr_src, out);

    // Layer 2 (out holds relu'd z1; H reused).
    gemm_mfma<OUT_DIM><<<NB_G, 256, 0, stream>>>(out, W2, H);
    agg_csr<<<NB_W, 256, 0, stream>>>(H, dinv, b2, off, csr_src, out);
}

// Round 16
// 123.906 us; speedup vs baseline: 2.6869x; 1.0012x over previous
//
#include <hip/hip_runtime.h>
#include <hip/hip_bf16.h>

#define N_NODES 50000
#define N_EDGES 800000
#define IN_DIM  256
#define OUT_DIM 64
#define CHUNKE  4096   // edges per radix chunk
#define NCHK    196    // ceil(800000/4096)
#define NBKT    196    // node buckets of 256
#define STAGE   12288  // LDS-staged CSR slice (ints)

using bf16x8 = __attribute__((ext_vector_type(8))) __bf16;
using f32x4  = __attribute__((ext_vector_type(4))) float;
using u32x4  = __attribute__((ext_vector_type(4))) unsigned int;

// ---------------------------------------------------------------------------
// MFMA split-bf16 GEMM (truncation split, 3 MFMA, rel err ~2^-16).
// A staged in LDS, DOUBLE-BUFFERED (8 KB x2): one barrier per 32-k chunk,
// next chunk's global loads issued before the barrier (latency overlapped).
// ---------------------------------------------------------------------------
union BFu { u32x4 u; bf16x8 b; };

__device__ __forceinline__ void split_pack(float x0, float x1,
                                           unsigned& hi, unsigned& lo) {
    unsigned u0 = __float_as_uint(x0), u1 = __float_as_uint(x1);
    hi = (u1 & 0xFFFF0000u) | (u0 >> 16);
    float h0 = __uint_as_float(u0 & 0xFFFF0000u);
    float h1 = __uint_as_float(u1 & 0xFFFF0000u);
    unsigned r0 = __float_as_uint(x0 - h0);
    unsigned r1 = __float_as_uint(x1 - h1);
    lo = (r1 & 0xFFFF0000u) | (r0 >> 16);
}

// lds: 16384 B = 2 x { a_hi[64][32]bf16 (4KB) + a_lo[64][32]bf16 (4KB) }
template <int K>
__device__ __forceinline__ void gemm_body(int gbid, const float* __restrict__ X,
                                          const float* __restrict__ W,
                                          float* __restrict__ H,
                                          char* lds) {
    constexpr int NS = K / 32;
    const int lane = threadIdx.x & 63;
    const int wave = threadIdx.x >> 6;   // output col tile 0..3
    const int lm   = lane & 15;
    const int kg   = lane >> 4;          // 0..3

    // B fragments (this wave's 16 cols), hi/lo, registers (static-indexed).
    BFu bhi[NS], blo[NS];
#pragma unroll
    for (int s = 0; s < NS; ++s) {
#pragma unroll
        for (int jp = 0; jp < 4; ++jp) {
            float w0 = W[(size_t)(s * 32 + kg * 8 + 2 * jp)     * 64 + wave * 16 + lm];
            float w1 = W[(size_t)(s * 32 + kg * 8 + 2 * jp + 1) * 64 + wave * 16 + lm];
            unsigned h, l;
            split_pack(w0, w1, h, l);
            bhi[s].u[jp] = h;
            blo[s].u[jp] = l;
        }
    }

    // Staging role: thread t stages row t>>2, k-offset (t&3)*8 (coalesced).
    const int srow = threadIdx.x >> 2;
    const int skc  = (threadIdx.x & 3) * 8;
    int gr = gbid * 64 + srow;
    const float* xs = X + (size_t)((gr < N_NODES) ? gr : (N_NODES - 1)) * K;

    f32x4 acc[4] = {};

    // prefetch chunk 0
    float4 c0 = *(const float4*)(xs + skc);
    float4 c1 = *(const float4*)(xs + skc + 4);

#pragma unroll
    for (int s = 0; s < NS; ++s) {
        unsigned short* a_hi = (unsigned short*)(lds + (s & 1) * 8192);
        unsigned short* a_lo = a_hi + 64 * 32;

        BFu h_, l_;
        unsigned h, l;
        split_pack(c0.x, c0.y, h, l); h_.u[0] = h; l_.u[0] = l;
        split_pack(c0.z, c0.w, h, l); h_.u[1] = h; l_.u[1] = l;
        split_pack(c1.x, c1.y, h, l); h_.u[2] = h; l_.u[2] = l;
        split_pack(c1.z, c1.w, h, l); h_.u[3] = h; l_.u[3] = l;
        *(u32x4*)(a_hi + srow * 32 + skc) = h_.u;
        *(u32x4*)(a_lo + srow * 32 + skc) = l_.u;

        if (s + 1 < NS) {   // issue next chunk's loads before the barrier
            c0 = *(const float4*)(xs + (s + 1) * 32 + skc);
            c1 = *(const float4*)(xs + (s + 1) * 32 + skc + 4);
        }

        __syncthreads();    // publish writes; prior chunk's reads already drained

#pragma unroll
        for (int m = 0; m < 4; ++m) {
            BFu ah, al;
            ah.u = *(const u32x4*)(a_hi + (m * 16 + lm) * 32 + kg * 8);
            al.u = *(const u32x4*)(a_lo + (m * 16 + lm) * 32 + kg * 8);
            acc[m] = __builtin_amdgcn_mfma_f32_16x16x32_bf16(ah.b, bhi[s].b, acc[m], 0, 0, 0);
            acc[m] = __builtin_amdgcn_mfma_f32_16x16x32_bf16(ah.b, blo[s].b, acc[m], 0, 0, 0);
            acc[m] = __builtin_amdgcn_mfma_f32_16x16x32_bf16(al.b, bhi[s].b, acc[m], 0, 0, 0);
        }
    }

    const int c = wave * 16 + lm;
#pragma unroll
    for (int m = 0; m < 4; ++m) {
#pragma unroll
        for (int t = 0; t < 4; ++t) {
            int r = gbid * 64 + m * 16 + kg * 4 + t;
            if (r < N_NODES) H[(size_t)r * 64 + c] = acc[m][t];
        }
    }
}

// ---------------------------------------------------------------------------
// Fused R1 + layer-1 GEMM (disjoint block ranges).
// ---------------------------------------------------------------------------
template <int K>
__global__ __launch_bounds__(256) void fused_hist_gemm1(const void* __restrict__ edges,
                                                        int* __restrict__ src32,
                                                        int* __restrict__ dst32,
                                                        int* __restrict__ hist,
                                                        const float* __restrict__ X,
                                                        const float* __restrict__ W,
                                                        float* __restrict__ H) {
    __shared__ char lds[16384];
    if ((int)blockIdx.x < NCHK) {
        int* h  = (int*)lds;          // 256 ints
        int* nz = (int*)(lds + 1024);
        if (threadIdx.x == 0) *nz = 0;
        h[threadIdx.x] = 0;
        __syncthreads();
        if (((const unsigned int*)edges)[2 * threadIdx.x + 1] != 0u) *nz = 1;
        __syncthreads();
        const int is64 = (*nz == 0);
        const int base = blockIdx.x * CHUNKE;
        for (int i = threadIdx.x; i < CHUNKE; i += 256) {
            int e = base + i;
            if (e < N_EDGES) {
                int s, d;
                if (is64) {
                    s = (int)((const long long*)edges)[e];
                    d = (int)((const long long*)edges)[(long long)N_EDGES + e];
                } else {
                    s = ((const int*)edges)[e];
                    d = ((const int*)edges)[(long long)N_EDGES + e];
                }
                src32[e] = s;
                dst32[e] = d;
                atomicAdd(&h[d >> 8], 1);
            }
        }
        __syncthreads();
        hist[blockIdx.x * 256 + threadIdx.x] = h[threadIdx.x];
    } else {
        gemm_body<K>((int)blockIdx.x - NCHK, X, W, H, lds);
    }
}

// ---------------------------------------------------------------------------
// R2: per-bin exclusive scan over chunks (in place); bsum[b] = bin total.
// ---------------------------------------------------------------------------
__global__ __launch_bounds__(64) void radix_scan(int* __restrict__ hist,
                                                 int* __restrict__ bsum) {
    const int b = blockIdx.x, l = threadIdx.x;
    int carry = 0;
#pragma unroll
    for (int seg = 0; seg < 4; ++seg) {
        int c = seg * 64 + l;
        int v = (c < NCHK) ? hist[c * 256 + b] : 0;
        int incl = v;
        for (int s = 1; s < 64; s <<= 1) {
            int t = __shfl_up(incl, s);
            if (l >= s) incl += t;
        }
        if (c < NCHK) hist[c * 256 + b] = incl - v + carry;
        carry += __shfl(incl, 63);
    }
    if (l == 0) bsum[b] = carry;
}

// ---------------------------------------------------------------------------
// R4: scatter to bucket-sorted COO (bases via in-LDS scan of bsum).
// ---------------------------------------------------------------------------
__global__ __launch_bounds__(256) void radix_scatter(const int* __restrict__ src32,
                                                     const int* __restrict__ dst32,
                                                     const int* __restrict__ hist,
                                                     const int* __restrict__ bsum,
                                                     int2* __restrict__ ebuf) {
    __shared__ int lcur[256];
    __shared__ int sm[256];
    __shared__ int sbase[256];
    const int t = threadIdx.x;
    int v = bsum[t];
    sm[t] = v;
    lcur[t] = 0;
    __syncthreads();
    for (int s = 1; s < 256; s <<= 1) {
        int tv = 0;
        if (t >= s) tv = sm[t - s];
        __syncthreads();
        if (t >= s) sm[t] += tv;
        __syncthreads();
    }
    sbase[t] = sm[t] - v;
    __syncthreads();
    const int base = blockIdx.x * CHUNKE;
    for (int i = t; i < CHUNKE; i += 256) {
        int e = base + i;
        if (e < N_EDGES) {
            int s = src32[e], d = dst32[e];
            int bin = d >> 8;
            int loc = atomicAdd(&lcur[bin], 1);
            int pos = sbase[bin] + hist[blockIdx.x * 256 + bin] + loc;
            ebuf[pos] = make_int2(s, d);
        }
    }
}

// ---------------------------------------------------------------------------
// R5: per-bucket finalize: off/dinv + LDS-staged coalesced CSR slice.
// ---------------------------------------------------------------------------
__global__ __launch_bounds__(256) void bucket_finalize(const int2* __restrict__ ebuf,
                                                       const int* __restrict__ bsum,
                                                       float* __restrict__ dinv,
                                                       int* __restrict__ off,
                                                       int* __restrict__ csr_src) {
    __shared__ int hist[256];
    __shared__ int sm[256];
    __shared__ int cur[256];
    __shared__ int stage[STAGE];
    __shared__ int beg_s, end_s;
    const int b = blockIdx.x, t = threadIdx.x;

    int v = bsum[t];
    sm[t] = v;
    __syncthreads();
    for (int s = 1; s < 256; s <<= 1) {
        int tv = 0;
        if (t >= s) tv = sm[t - s];
        __syncthreads();
        if (t >= s) sm[t] += tv;
        __syncthreads();
    }
    if (t == b) { beg_s = sm[t] - v; end_s = sm[t]; }
    __syncthreads();
    const int beg = beg_s, end = end_s, size = end - beg;

    hist[t] = 0;
    __syncthreads();
    for (int e = beg + t; e < end; e += 256) atomicAdd(&hist[ebuf[e].y & 255], 1);
    __syncthreads();

    v = hist[t];
    sm[t] = v;
    __syncthreads();
    for (int s = 1; s < 256; s <<= 1) {
        int tv = 0;
        if (t >= s) tv = sm[t - s];
        __syncthreads();
        if (t >= s) sm[t] += tv;
        __syncthreads();
    }
    int pre = sm[t] - v;

    int node = b * 256 + t;
    if (node < N_NODES) {
        off[node] = beg + pre;
        dinv[node] = rsqrtf((float)(v + 1));
    }
    if (b == NBKT - 1 && t == 0) off[N_NODES] = end;

    cur[t] = pre;
    __syncthreads();

    if (size <= STAGE) {
        for (int e = beg + t; e < end; e += 256) {
            int2 ed = ebuf[e];
            int p = atomicAdd(&cur[ed.y & 255], 1);
            stage[p] = ed.x;
        }
        __syncthreads();
        for (int i = t; i < size; i += 256) csr_src[beg + i] = stage[i];
    } else {
        for (int e = beg + t; e < end; e += 256) {
            int2 ed = ebuf[e];
            int p = atomicAdd(&cur[ed.y & 255], 1);
            csr_src[beg + p] = ed.x;
        }
    }
}

template <int K>
__global__ __launch_bounds__(256) void gemm_mfma(const float* __restrict__ X,
                                                 const float* __restrict__ W,
                                                 float* __restrict__ H) {
    __shared__ char lds[16384];
    gemm_body<K>((int)blockIdx.x, X, W, H, lds);
}

// ---------------------------------------------------------------------------
// Gather-aggregate: one wave per dst node, lane = column.
// out = relu( (Σ_s H[s]*dinv[s] + H[d]*dd) * dd + b )
// ---------------------------------------------------------------------------
__global__ __launch_bounds__(256) void agg_csr(const float* __restrict__ H,
                                               const float* __restrict__ dinv,
                                               const float* __restrict__ b,
                                               const int* __restrict__ off,
                                               const int* __restrict__ csr_src,
                                               float* __restrict__ out) {
    int wid  = (blockIdx.x * 256 + threadIdx.x) >> 6;
    int lane = threadIdx.x & 63;
    if (wid >= N_NODES) return;
    float dd = dinv[wid];
    float acc = H[(size_t)wid * 64 + lane] * dd;
    int beg = off[wid], end = off[wid + 1];
    for (int k0 = beg; k0 < end; k0 += 64) {
        int myk = k0 + lane;
        int   s_l  = (myk < end) ? csr_src[myk] : 0;
        float ds_l = (myk < end) ? dinv[s_l] : 0.f;
        int cnt = min(64, end - k0);
        int i = 0;
        for (; i + 8 <= cnt; i += 8) {
            float v[8], nm[8];
#pragma unroll
            for (int jj = 0; jj < 8; ++jj) {
                int s  = __shfl(s_l, i + jj);
                nm[jj] = __shfl(ds_l, i + jj);
                v[jj]  = H[(size_t)s * 64 + lane];
            }
#pragma unroll
            for (int jj = 0; jj < 8; ++jj) acc = fmaf(v[jj], nm[jj], acc);
        }
        for (; i < cnt; ++i) {
            int   s  = __shfl(s_l, i);
            float nm = __shfl(ds_l, i);
            acc = fmaf(H[(size_t)s * 64 + lane], nm, acc);
        }
    }
    out[(size_t)wid * 64 + lane] = fmaxf(fmaf(acc, dd, b[lane]), 0.f);
}

extern "C" void kernel_launch(void* const* d_in, const int* in_sizes, int n_in,
                              void* d_out, int out_size, void* d_ws, size_t ws_size,
                              hipStream_t stream) {
    const float* feat = (const float*)d_in[0];
    const float* W1   = (const float*)d_in[1];
    const float* b1   = (const float*)d_in[2];
    const float* W2   = (const float*)d_in[3];
    const float* b2   = (const float*)d_in[4];
    const void*  edges = d_in[5];
    float* out = (float*)d_out;

    char* ws = (char*)d_ws;
    const size_t SZ_E = (size_t)N_EDGES * 4;
    int*   bsum    = (int*)(ws + 2048);                          // 256 ints
    int*   hist    = (int*)(ws + 4096);                          // 196*256 ints
    float* dinv    = (float*)(ws + 4096 + 204800);               // 50000 f32
    int*   off     = (int*)(ws + 4096 + 204800 + 204800);        // 50001 ints
    size_t o = 4096 + 3 * 204800;
    int*   src32   = (int*)(ws + o);              o += SZ_E;     // 3.2 MB
    int*   dst32   = (int*)(ws + o);              o += SZ_E;     // 3.2 MB
    int2*  ebuf    = (int2*)(ws + o);             o += 2 * SZ_E; // 6.4 MB
    int*   csr_src = (int*)(ws + o);              o += SZ_E;     // 3.2 MB
    float* H       = (float*)(ws + o);                           // 12.8 MB

    const int NB_G = (N_NODES + 63) / 64;         // 782
    const int NB_W = (N_NODES * 64 + 255) / 256;  // 12500

    // R1 + layer-1 GEMM fused (hist hides under gemm1).
    fused_hist_gemm1<IN_DIM><<<NCHK + NB_G, 256, 0, stream>>>(
        edges, src32, dst32, hist, feat, W1, H);
    radix_scan<<<256, 64, 0, stream>>>(hist, bsum);
    radix_scatter<<<NCHK, 256, 0, stream>>>(src32, dst32, hist, bsum, ebuf);
    bucket_finalize<<<NBKT, 256, 0, stream>>>(ebuf, bsum, dinv, off, csr_src);

    // Layer 1 aggregate.
    agg_csr<<<NB_W, 256, 0, stream>>>(H, dinv, b1, off, csr_src, out);

    // Layer 2 (out holds relu'd z1; H reused).
    gemm_mfma<OUT_DIM><<<NB_G, 256, 0, stream>>>(out, W2, H);
    agg_csr<<<NB_W, 256, 0, stream>>>(H, dinv, b2, off, csr_src, out);
}

// Round 17
// 114.768 us; speedup vs baseline: 2.9009x; 1.0796x over previous
//
#include <hip/hip_runtime.h>
#include <hip/hip_bf16.h>

#define N_NODES 50000
#define N_EDGES 800000
#define IN_DIM  256
#define OUT_DIM 64
#define CHUNKE  4096   // edges per radix chunk
#define NCHK    196    // ceil(800000/4096)
#define NBKT    196    // node buckets of 256
#define STAGE   12288  // LDS-staged CSR slice (ints)

using bf16x8 = __attribute__((ext_vector_type(8))) __bf16;
using f32x4  = __attribute__((ext_vector_type(4))) float;
using u32x4  = __attribute__((ext_vector_type(4))) unsigned int;

// ---------------------------------------------------------------------------
// MFMA split-bf16 GEMM (truncation split, 3 MFMA, rel err ~2^-16).
// A staged in LDS, double-buffered. H output stored BF16 (RN): halves the
// downstream gather traffic (agg is cache-byte-bound).
// ---------------------------------------------------------------------------
union BFu { u32x4 u; bf16x8 b; };

__device__ __forceinline__ void split_pack(float x0, float x1,
                                           unsigned& hi, unsigned& lo) {
    unsigned u0 = __float_as_uint(x0), u1 = __float_as_uint(x1);
    hi = (u1 & 0xFFFF0000u) | (u0 >> 16);
    float h0 = __uint_as_float(u0 & 0xFFFF0000u);
    float h1 = __uint_as_float(u1 & 0xFFFF0000u);
    unsigned r0 = __float_as_uint(x0 - h0);
    unsigned r1 = __float_as_uint(x1 - h1);
    lo = (r1 & 0xFFFF0000u) | (r0 >> 16);
}

__device__ __forceinline__ unsigned short bf16_rn(float x) {
    unsigned u = __float_as_uint(x);
    unsigned r = u + 0x7FFFu + ((u >> 16) & 1u);
    return (unsigned short)(r >> 16);
}

// lds: 16384 B = 2 x { a_hi[64][32]bf16 (4KB) + a_lo[64][32]bf16 (4KB) }
template <int K>
__device__ __forceinline__ void gemm_body(int gbid, const float* __restrict__ X,
                                          const float* __restrict__ W,
                                          unsigned short* __restrict__ H,
                                          char* lds) {
    constexpr int NS = K / 32;
    const int lane = threadIdx.x & 63;
    const int wave = threadIdx.x >> 6;   // output col tile 0..3
    const int lm   = lane & 15;
    const int kg   = lane >> 4;          // 0..3

    BFu bhi[NS], blo[NS];
#pragma unroll
    for (int s = 0; s < NS; ++s) {
#pragma unroll
        for (int jp = 0; jp < 4; ++jp) {
            float w0 = W[(size_t)(s * 32 + kg * 8 + 2 * jp)     * 64 + wave * 16 + lm];
            float w1 = W[(size_t)(s * 32 + kg * 8 + 2 * jp + 1) * 64 + wave * 16 + lm];
            unsigned h, l;
            split_pack(w0, w1, h, l);
            bhi[s].u[jp] = h;
            blo[s].u[jp] = l;
        }
    }

    const int srow = threadIdx.x >> 2;
    const int skc  = (threadIdx.x & 3) * 8;
    int gr = gbid * 64 + srow;
    const float* xs = X + (size_t)((gr < N_NODES) ? gr : (N_NODES - 1)) * K;

    f32x4 acc[4] = {};

    float4 c0 = *(const float4*)(xs + skc);
    float4 c1 = *(const float4*)(xs + skc + 4);

#pragma unroll
    for (int s = 0; s < NS; ++s) {
        unsigned short* a_hi = (unsigned short*)(lds + (s & 1) * 8192);
        unsigned short* a_lo = a_hi + 64 * 32;

        BFu h_, l_;
        unsigned h, l;
        split_pack(c0.x, c0.y, h, l); h_.u[0] = h; l_.u[0] = l;
        split_pack(c0.z, c0.w, h, l); h_.u[1] = h; l_.u[1] = l;
        split_pack(c1.x, c1.y, h, l); h_.u[2] = h; l_.u[2] = l;
        split_pack(c1.z, c1.w, h, l); h_.u[3] = h; l_.u[3] = l;
        *(u32x4*)(a_hi + srow * 32 + skc) = h_.u;
        *(u32x4*)(a_lo + srow * 32 + skc) = l_.u;

        if (s + 1 < NS) {
            c0 = *(const float4*)(xs + (s + 1) * 32 + skc);
            c1 = *(const float4*)(xs + (s + 1) * 32 + skc + 4);
        }

        __syncthreads();

#pragma unroll
        for (int m = 0; m < 4; ++m) {
            BFu ah, al;
            ah.u = *(const u32x4*)(a_hi + (m * 16 + lm) * 32 + kg * 8);
            al.u = *(const u32x4*)(a_lo + (m * 16 + lm) * 32 + kg * 8);
            acc[m] = __builtin_amdgcn_mfma_f32_16x16x32_bf16(ah.b, bhi[s].b, acc[m], 0, 0, 0);
            acc[m] = __builtin_amdgcn_mfma_f32_16x16x32_bf16(ah.b, blo[s].b, acc[m], 0, 0, 0);
            acc[m] = __builtin_amdgcn_mfma_f32_16x16x32_bf16(al.b, bhi[s].b, acc[m], 0, 0, 0);
        }
    }

    const int c = wave * 16 + lm;
#pragma unroll
    for (int m = 0; m < 4; ++m) {
#pragma unroll
        for (int t = 0; t < 4; ++t) {
            int r = gbid * 64 + m * 16 + kg * 4 + t;
            if (r < N_NODES) H[(size_t)r * 64 + c] = bf16_rn(acc[m][t]);
        }
    }
}

// ---------------------------------------------------------------------------
// Fused R1 + layer-1 GEMM (disjoint block ranges).
// ---------------------------------------------------------------------------
template <int K>
__global__ __launch_bounds__(256) void fused_hist_gemm1(const void* __restrict__ edges,
                                                        int* __restrict__ src32,
                                                        int* __restrict__ dst32,
                                                        int* __restrict__ hist,
                                                        const float* __restrict__ X,
                                                        const float* __restrict__ W,
                                                        unsigned short* __restrict__ H) {
    __shared__ char lds[16384];
    if ((int)blockIdx.x < NCHK) {
        int* h  = (int*)lds;
        int* nz = (int*)(lds + 1024);
        if (threadIdx.x == 0) *nz = 0;
        h[threadIdx.x] = 0;
        __syncthreads();
        if (((const unsigned int*)edges)[2 * threadIdx.x + 1] != 0u) *nz = 1;
        __syncthreads();
        const int is64 = (*nz == 0);
        const int base = blockIdx.x * CHUNKE;
        for (int i = threadIdx.x; i < CHUNKE; i += 256) {
            int e = base + i;
            if (e < N_EDGES) {
                int s, d;
                if (is64) {
                    s = (int)((const long long*)edges)[e];
                    d = (int)((const long long*)edges)[(long long)N_EDGES + e];
                } else {
                    s = ((const int*)edges)[e];
                    d = ((const int*)edges)[(long long)N_EDGES + e];
                }
                src32[e] = s;
                dst32[e] = d;
                atomicAdd(&h[d >> 8], 1);
            }
        }
        __syncthreads();
        hist[blockIdx.x * 256 + threadIdx.x] = h[threadIdx.x];
    } else {
        gemm_body<K>((int)blockIdx.x - NCHK, X, W, H, lds);
    }
}

// ---------------------------------------------------------------------------
// R2: per-bin exclusive scan over chunks (in place); bsum[b] = bin total.
// ---------------------------------------------------------------------------
__global__ __launch_bounds__(64) void radix_scan(int* __restrict__ hist,
                                                 int* __restrict__ bsum) {
    const int b = blockIdx.x, l = threadIdx.x;
    int carry = 0;
#pragma unroll
    for (int seg = 0; seg < 4; ++seg) {
        int c = seg * 64 + l;
        int v = (c < NCHK) ? hist[c * 256 + b] : 0;
        int incl = v;
        for (int s = 1; s < 64; s <<= 1) {
            int t = __shfl_up(incl, s);
            if (l >= s) incl += t;
        }
        if (c < NCHK) hist[c * 256 + b] = incl - v + carry;
        carry += __shfl(incl, 63);
    }
    if (l == 0) bsum[b] = carry;
}

// ---------------------------------------------------------------------------
// R4: scatter to bucket-sorted COO (bases via in-LDS scan of bsum).
// ---------------------------------------------------------------------------
__global__ __launch_bounds__(256) void radix_scatter(const int* __restrict__ src32,
                                                     const int* __restrict__ dst32,
                                                     const int* __restrict__ hist,
                                                     const int* __restrict__ bsum,
                                                     int2* __restrict__ ebuf) {
    __shared__ int lcur[256];
    __shared__ int sm[256];
    __shared__ int sbase[256];
    const int t = threadIdx.x;
    int v = bsum[t];
    sm[t] = v;
    lcur[t] = 0;
    __syncthreads();
    for (int s = 1; s < 256; s <<= 1) {
        int tv = 0;
        if (t >= s) tv = sm[t - s];
        __syncthreads();
        if (t >= s) sm[t] += tv;
        __syncthreads();
    }
    sbase[t] = sm[t] - v;
    __syncthreads();
    const int base = blockIdx.x * CHUNKE;
    for (int i = t; i < CHUNKE; i += 256) {
        int e = base + i;
        if (e < N_EDGES) {
            int s = src32[e], d = dst32[e];
            int bin = d >> 8;
            int loc = atomicAdd(&lcur[bin], 1);
            int pos = sbase[bin] + hist[blockIdx.x * 256 + bin] + loc;
            ebuf[pos] = make_int2(s, d);
        }
    }
}

// ---------------------------------------------------------------------------
// R5: per-bucket finalize: off/dinv + LDS-staged coalesced CSR slice.
// ---------------------------------------------------------------------------
__global__ __launch_bounds__(256) void bucket_finalize(const int2* __restrict__ ebuf,
                                                       const int* __restrict__ bsum,
                                                       float* __restrict__ dinv,
                                                       int* __restrict__ off,
                                                       int* __restrict__ csr_src) {
    __shared__ int hist[256];
    __shared__ int sm[256];
    __shared__ int cur[256];
    __shared__ int stage[STAGE];
    __shared__ int beg_s, end_s;
    const int b = blockIdx.x, t = threadIdx.x;

    int v = bsum[t];
    sm[t] = v;
    __syncthreads();
    for (int s = 1; s < 256; s <<= 1) {
        int tv = 0;
        if (t >= s) tv = sm[t - s];
        __syncthreads();
        if (t >= s) sm[t] += tv;
        __syncthreads();
    }
    if (t == b) { beg_s = sm[t] - v; end_s = sm[t]; }
    __syncthreads();
    const int beg = beg_s, end = end_s, size = end - beg;

    hist[t] = 0;
    __syncthreads();
    for (int e = beg + t; e < end; e += 256) atomicAdd(&hist[ebuf[e].y & 255], 1);
    __syncthreads();

    v = hist[t];
    sm[t] = v;
    __syncthreads();
    for (int s = 1; s < 256; s <<= 1) {
        int tv = 0;
        if (t >= s) tv = sm[t - s];
        __syncthreads();
        if (t >= s) sm[t] += tv;
        __syncthreads();
    }
    int pre = sm[t] - v;

    int node = b * 256 + t;
    if (node < N_NODES) {
        off[node] = beg + pre;
        dinv[node] = rsqrtf((float)(v + 1));
    }
    if (b == NBKT - 1 && t == 0) off[N_NODES] = end;

    cur[t] = pre;
    __syncthreads();

    if (size <= STAGE) {
        for (int e = beg + t; e < end; e += 256) {
            int2 ed = ebuf[e];
            int p = atomicAdd(&cur[ed.y & 255], 1);
            stage[p] = ed.x;
        }
        __syncthreads();
        for (int i = t; i < size; i += 256) csr_src[beg + i] = stage[i];
    } else {
        for (int e = beg + t; e < end; e += 256) {
            int2 ed = ebuf[e];
            int p = atomicAdd(&cur[ed.y & 255], 1);
            csr_src[beg + p] = ed.x;
        }
    }
}

template <int K>
__global__ __launch_bounds__(256) void gemm_mfma(const float* __restrict__ X,
                                                 const float* __restrict__ W,
                                                 unsigned short* __restrict__ H) {
    __shared__ char lds[16384];
    gemm_body<K>((int)blockIdx.x, X, W, H, lds);
}

// ---------------------------------------------------------------------------
// Gather-aggregate: one wave per dst node, lane = column. H is BF16 ->
// half the gather bytes; f32 accumulate.
// out = relu( (Σ_s H[s]*dinv[s] + H[d]*dd) * dd + b )
// ---------------------------------------------------------------------------
__device__ __forceinline__ float bf2f(unsigned short u) {
    return __uint_as_float((unsigned)u << 16);
}

__global__ __launch_bounds__(256) void agg_csr(const unsigned short* __restrict__ H,
                                               const float* __restrict__ dinv,
                                               const float* __restrict__ b,
                                               const int* __restrict__ off,
                                               const int* __restrict__ csr_src,
                                               float* __restrict__ out) {
    int wid  = (blockIdx.x * 256 + threadIdx.x) >> 6;
    int lane = threadIdx.x & 63;
    if (wid >= N_NODES) return;
    float dd = dinv[wid];
    float acc = bf2f(H[(size_t)wid * 64 + lane]) * dd;
    int beg = off[wid], end = off[wid + 1];
    for (int k0 = beg; k0 < end; k0 += 64) {
        int myk = k0 + lane;
        int   s_l  = (myk < end) ? csr_src[myk] : 0;
        float ds_l = (myk < end) ? dinv[s_l] : 0.f;
        int cnt = min(64, end - k0);
        int i = 0;
        for (; i + 8 <= cnt; i += 8) {
            float v[8], nm[8];
#pragma unroll
            for (int jj = 0; jj < 8; ++jj) {
                int s  = __shfl(s_l, i + jj);
                nm[jj] = __shfl(ds_l, i + jj);
                v[jj]  = bf2f(H[(size_t)s * 64 + lane]);
            }
#pragma unroll
            for (int jj = 0; jj < 8; ++jj) acc = fmaf(v[jj], nm[jj], acc);
        }
        for (; i < cnt; ++i) {
            int   s  = __shfl(s_l, i);
            float nm = __shfl(ds_l, i);
            acc = fmaf(bf2f(H[(size_t)s * 64 + lane]), nm, acc);
        }
    }
    out[(size_t)wid * 64 + lane] = fmaxf(fmaf(acc, dd, b[lane]), 0.f);
}

extern "C" void kernel_launch(void* const* d_in, const int* in_sizes, int n_in,
                              void* d_out, int out_size, void* d_ws, size_t ws_size,
                              hipStream_t stream) {
    const float* feat = (const float*)d_in[0];
    const float* W1   = (const float*)d_in[1];
    const float* b1   = (const float*)d_in[2];
    const float* W2   = (const float*)d_in[3];
    const float* b2   = (const float*)d_in[4];
    const void*  edges = d_in[5];
    float* out = (float*)d_out;

    char* ws = (char*)d_ws;
    const size_t SZ_E = (size_t)N_EDGES * 4;
    int*   bsum    = (int*)(ws + 2048);                          // 256 ints
    int*   hist    = (int*)(ws + 4096);                          // 196*256 ints
    float* dinv    = (float*)(ws + 4096 + 204800);               // 50000 f32
    int*   off     = (int*)(ws + 4096 + 204800 + 204800);        // 50001 ints
    size_t o = 4096 + 3 * 204800;
    int*   src32   = (int*)(ws + o);              o += SZ_E;     // 3.2 MB
    int*   dst32   = (int*)(ws + o);              o += SZ_E;     // 3.2 MB
    int2*  ebuf    = (int2*)(ws + o);             o += 2 * SZ_E; // 6.4 MB
    int*   csr_src = (int*)(ws + o);              o += SZ_E;     // 3.2 MB
    unsigned short* H = (unsigned short*)(ws + o);               // 6.4 MB (bf16)

    const int NB_G = (N_NODES + 63) / 64;         // 782
    const int NB_W = (N_NODES * 64 + 255) / 256;  // 12500

    // R1 + layer-1 GEMM fused (hist hides under gemm1).
    fused_hist_gemm1<IN_DIM><<<NCHK + NB_G, 256, 0, stream>>>(
        edges, src32, dst32, hist, feat, W1, H);
    radix_scan<<<256, 64, 0, stream>>>(hist, bsum);
    radix_scatter<<<NCHK, 256, 0, stream>>>(src32, dst32, hist, bsum, ebuf);
    bucket_finalize<<<NBKT, 256, 0, stream>>>(ebuf, bsum, dinv, off, csr_src);

    // Layer 1 aggregate.
    agg_csr<<<NB_W, 256, 0, stream>>>(H, dinv, b1, off, csr_src, out);

    // Layer 2 (out holds relu'd z1; H reused).
    gemm_mfma<OUT_DIM><<<NB_G, 256, 0, stream>>>(out, W2, H);
    agg_csr<<<NB_W, 256, 0, stream>>>(H, dinv, b2, off, csr_src, out);
}